// Round 2
// baseline (262.555 us; speedup 1.0000x reference)
//
#include <hip/hip_runtime.h>
#include <stdint.h>
#include <math.h>

#define NB 16
#define NP 6000
#define NG 128
#define NC 10
#define CHUNK 24     // ceil(NP/256)
#define SELMAX 8     // dyn <= 4 for head_idx=5; slack for safety

static_assert(CHUNK * 256 >= NP, "chunk covers P");

typedef unsigned long long u64;

__device__ __forceinline__ uint32_t fkey(float f) {
  // monotone float->uint mapping for (cost, idx) lexicographic min
  uint32_t u = __float_as_uint(f);
  return (u & 0x80000000u) ? ~u : (u | 0x80000000u);
}

// ---------------------------------------------------------------------------
// Per-GT derived quantities: aabb(gmin,gmax), center-radius box(lo,hi),
// gt_norm[8], volume, label.  Layout: 22 floats per (b,g).
__global__ void prep_gt_kernel(const float* __restrict__ gt_boxes,
                               const int* __restrict__ gt_labels,
                               float* __restrict__ gtaux) {
#pragma clang fp contract(off)
  int b = blockIdx.x, g = threadIdx.x;
  if (g >= NG) return;
  const float* gb = gt_boxes + ((size_t)b * NG + g) * 7;
  float cx = gb[0], cy = gb[1], cz = gb[2];
  float dx = gb[3], dy = gb[4], dz = gb[5];
  float yaw = gb[6];
  float cyw = cosf(yaw), syw = sinf(yaw);
  float ca = fabsf(cyw), sa = fabsf(syw);
  float hx = 0.5f * (dx * ca + dy * sa);
  float hy = 0.5f * (dx * sa + dy * ca);
  float hz = 0.5f * dz;
  float gmin0 = cx - hx, gmin1 = cy - hy, gmin2 = cz - hz;
  float gmax0 = cx + hx, gmax1 = cy + hy, gmax2 = cz + hz;
  float vg = ((gmax0 - gmin0) * (gmax1 - gmin1)) * (gmax2 - gmin2);
  float* o = gtaux + ((size_t)b * NG + g) * 22;
  o[0] = gmin0; o[1] = gmin1; o[2] = gmin2;
  o[3] = gmax0; o[4] = gmax1; o[5] = gmax2;
  o[6] = cx - 1.5f * dx; o[7] = cy - 1.5f * dy; o[8] = cz - 1.5f * dz;
  o[9] = cx + 1.5f * dx; o[10] = cy + 1.5f * dy; o[11] = cz + 1.5f * dz;
  o[12] = cx; o[13] = cy; o[14] = cz;
  o[15] = logf(dx); o[16] = logf(dy); o[17] = logf(dz);
  o[18] = syw; o[19] = cyw;
  o[20] = vg;
  o[21] = __int_as_float(gt_labels[(size_t)b * NG + g]);
}

// ---------------------------------------------------------------------------
// Per-pred: focal-loss class table (10), raw box dims (8), pred aabb + volume,
// and valid flag (any in_box OR any in_ctr over all g).  SoA layout for
// coalesced column-kernel reads.
__global__ __launch_bounds__(256) void prep_pred_kernel(
    const float* __restrict__ pred_logits,
    const float* __restrict__ pred_boxes,
    const float* __restrict__ gtaux,
    float* __restrict__ paux,    // 15 * NB*NP
    float* __restrict__ clst,    // NC * NB*NP
    int* __restrict__ validArr) {
#pragma clang fp contract(off)
  __shared__ float shg[NG * 12];
  int b = blockIdx.y, tid = threadIdx.x;
  for (int j = tid; j < NG * 12; j += 256) {
    int g = j / 12, k = j % 12;
    shg[j] = gtaux[((size_t)b * NG + g) * 22 + k];
  }
  __syncthreads();
  int p = blockIdx.x * 256 + tid;
  if (p >= NP) return;
  const size_t NBPs = (size_t)NB * NP;
  size_t idx = (size_t)b * NP + p;
  const float* lg = pred_logits + idx * NC;
  const float* bx = pred_boxes + idx * 10;
  for (int c = 0; c < NC; ++c) {
    float x = lg[c];
    float pr = 1.0f / (1.0f + expf(-x));
    float neg = (-logf(1.0f - pr + 1e-12f) * 0.75f) * (pr * pr);
    float pos = (-logf(pr + 1e-12f) * 0.25f) * ((1.0f - pr) * (1.0f - pr));
    clst[(size_t)c * NBPs + idx] = (pos - neg) * 2.0f;
  }
  float b0 = bx[0], b1 = bx[1], b2 = bx[2], b3 = bx[3], b4 = bx[4];
  float b5 = bx[5], b6 = bx[6], b7 = bx[7];
  float yaw = atan2f(b6, b7);
  float d0 = expf(b3), d1 = expf(b4), d2 = expf(b5);
  float ca = fabsf(cosf(yaw)), sa = fabsf(sinf(yaw));
  float hx = 0.5f * (d0 * ca + d1 * sa);
  float hy = 0.5f * (d0 * sa + d1 * ca);
  float hz = 0.5f * d2;
  float pmin0 = b0 - hx, pmin1 = b1 - hy, pmin2 = b2 - hz;
  float pmax0 = b0 + hx, pmax1 = b1 + hy, pmax2 = b2 + hz;
  float vp = ((pmax0 - pmin0) * (pmax1 - pmin1)) * (pmax2 - pmin2);
  int valid = 0;
  for (int g = 0; g < NG; ++g) {
    const float* s = &shg[g * 12];
    bool inb = (b0 > s[0]) && (b0 < s[3]) && (b1 > s[1]) && (b1 < s[4]) &&
               (b2 > s[2]) && (b2 < s[5]);
    bool inc = (b0 > s[6]) && (b0 < s[9]) && (b1 > s[7]) && (b1 < s[10]) &&
               (b2 > s[8]) && (b2 < s[11]);
    if (inb || inc) { valid = 1; break; }
  }
  paux[0 * NBPs + idx] = b0;  paux[1 * NBPs + idx] = b1;
  paux[2 * NBPs + idx] = b2;  paux[3 * NBPs + idx] = b3;
  paux[4 * NBPs + idx] = b4;  paux[5 * NBPs + idx] = b5;
  paux[6 * NBPs + idx] = b6;  paux[7 * NBPs + idx] = b7;
  paux[8 * NBPs + idx] = pmin0;  paux[9 * NBPs + idx] = pmin1;
  paux[10 * NBPs + idx] = pmin2; paux[11 * NBPs + idx] = pmax0;
  paux[12 * NBPs + idx] = pmax1; paux[13 * NBPs + idx] = pmax2;
  paux[14 * NBPs + idx] = vp;
  validArr[idx] = valid;
}

__global__ void init_kernel(int* __restrict__ rowcnt, int* __restrict__ rowassign) {
  int i = blockIdx.x * 256 + threadIdx.x;
  if (i >= NB * NP) return;
  rowcnt[i] = 0;
  rowassign[i] = 0x7fffffff;
}

// ---------------------------------------------------------------------------
// One block per (g,b) column: compute the full cost column (write to global),
// top-5 iou -> dyn, then dyn sequential argmin passes over register-resident
// costs to select the dyn smallest (cost,p).  atomicAdd rowcnt / atomicMin
// rowassign record the initial matching.
__global__ __launch_bounds__(256) void column_kernel(
    const float* __restrict__ paux,
    const float* __restrict__ clst,
    const int* __restrict__ validArr,
    const float* __restrict__ gtaux,
    const int* __restrict__ head_ptr,
    float* __restrict__ cost,
    int* __restrict__ colsel,
    int* __restrict__ rowcnt,
    int* __restrict__ rowassign) {
#pragma clang fp contract(off)
  const int g = blockIdx.x, b = blockIdx.y, tid = threadIdx.x;
  const float* ga = gtaux + ((size_t)b * NG + g) * 22;
  const float gmin0 = ga[0], gmin1 = ga[1], gmin2 = ga[2];
  const float gmax0 = ga[3], gmax1 = ga[4], gmax2 = ga[5];
  const float lo0 = ga[6], lo1 = ga[7], lo2 = ga[8];
  const float hi0 = ga[9], hi1 = ga[10], hi2 = ga[11];
  float gtn[8];
#pragma unroll
  for (int d = 0; d < 8; ++d) gtn[d] = ga[12 + d];
  const float vg = ga[20];
  const int label = __float_as_int(ga[21]);
  const size_t NBPs = (size_t)NB * NP;
  const size_t rowbase = (size_t)b * NP;
  const size_t cbase = ((size_t)(b * NG + g)) * NP;

  float lc[CHUNK];
  float t5[5];
#pragma unroll
  for (int j = 0; j < 5; ++j) t5[j] = -INFINITY;

#pragma unroll
  for (int i = 0; i < CHUNK; ++i) {
    int p = i * 256 + tid;
    float cv = INFINITY;
    if (p < NP) {
      size_t idx = rowbase + p;
      float pb0 = paux[0 * NBPs + idx], pb1 = paux[1 * NBPs + idx];
      float pb2 = paux[2 * NBPs + idx], pb3 = paux[3 * NBPs + idx];
      float pb4 = paux[4 * NBPs + idx], pb5 = paux[5 * NBPs + idx];
      float pb6 = paux[6 * NBPs + idx], pb7 = paux[7 * NBPs + idx];
      float pmin0 = paux[8 * NBPs + idx], pmin1 = paux[9 * NBPs + idx];
      float pmin2 = paux[10 * NBPs + idx], pmax0 = paux[11 * NBPs + idx];
      float pmax1 = paux[12 * NBPs + idx], pmax2 = paux[13 * NBPs + idx];
      float vp = paux[14 * NBPs + idx];
      float cls = clst[(size_t)label * NBPs + idx];
      // sequential 8-term L1, then * REG_W (mirrors jnp sum order)
      float r = fabsf(pb0 - gtn[0]);
      r = r + fabsf(pb1 - gtn[1]);
      r = r + fabsf(pb2 - gtn[2]);
      r = r + fabsf(pb3 - gtn[3]);
      r = r + fabsf(pb4 - gtn[4]);
      r = r + fabsf(pb5 - gtn[5]);
      r = r + fabsf(pb6 - gtn[6]);
      r = r + fabsf(pb7 - gtn[7]);
      float reg = r * 0.25f;
      float li0 = fmaxf(pmin0, gmin0), li1 = fmaxf(pmin1, gmin1), li2 = fmaxf(pmin2, gmin2);
      float hj0 = fminf(pmax0, gmax0), hj1 = fminf(pmax1, gmax1), hj2 = fminf(pmax2, gmax2);
      float e0 = fmaxf(hj0 - li0, 0.0f), e1 = fmaxf(hj1 - li1, 0.0f), e2 = fmaxf(hj2 - li2, 0.0f);
      float inter = (e0 * e1) * e2;
      float iou = inter / (((vp + vg) - inter) + 1e-7f);
      bool inb = (pb0 > gmin0) && (pb0 < gmax0) && (pb1 > gmin1) &&
                 (pb1 < gmax1) && (pb2 > gmin2) && (pb2 < gmax2);
      bool inc = (pb0 > lo0) && (pb0 < hi0) && (pb1 > lo1) && (pb1 < hi1) &&
                 (pb2 > lo2) && (pb2 < hi2);
      float cc = ((cls + reg) + (-(iou * 0.25f))) + ((inb && inc) ? 0.0f : 100.0f);
      cc = cc + (validArr[idx] ? 0.0f : 10000.0f);
      cost[cbase + p] = cc;
      cv = cc;
      if (iou > t5[4]) {
        t5[4] = iou;
#pragma unroll
        for (int j = 4; j > 0; --j) {
          if (t5[j] > t5[j - 1]) { float tmp = t5[j]; t5[j] = t5[j - 1]; t5[j - 1] = tmp; }
        }
      }
    }
    lc[i] = cv;
  }

  // top-5 iou block reduce -> dyn
  __shared__ float sh5[256 * 5];
#pragma unroll
  for (int j = 0; j < 5; ++j) sh5[tid * 5 + j] = t5[j];
  __syncthreads();
  __shared__ int s_dyn;
  if (tid == 0) {
    float m[5] = {-INFINITY, -INFINITY, -INFINITY, -INFINITY, -INFINITY};
    for (int j = 0; j < 256 * 5; ++j) {
      float v = sh5[j];
      if (v > m[4]) {
        m[4] = v;
#pragma unroll
        for (int q = 4; q > 0; --q) {
          if (m[q] > m[q - 1]) { float tmp = m[q]; m[q] = m[q - 1]; m[q - 1] = tmp; }
        }
      }
    }
    float s = ((((m[0] + m[1]) + m[2]) + m[3]) + m[4]);  // descending order sum
    float adj = s - 0.5f * (float)(6 - head_ptr[0]);
    int dyn = (int)adj;          // trunc toward zero, as astype(int32)
    if (dyn < 1) dyn = 1;
    if (dyn > SELMAX) dyn = SELMAX;
    s_dyn = dyn;
  }
  __syncthreads();
  const int dyn = s_dyn;

  // dyn passes of argmin with exclusion == stable-rank < dyn selection
  __shared__ u64 red[256];
  __shared__ int s_sel[SELMAX];
  for (int k = 0; k < dyn; ++k) {
    u64 best = ~0ull;
#pragma unroll
    for (int i = 0; i < CHUNK; ++i) {
      int p = i * 256 + tid;
      bool ok = (p < NP);
      for (int j = 0; j < k; ++j) ok = ok && (p != s_sel[j]);
      if (ok) {
        u64 key = ((u64)fkey(lc[i]) << 32) | (unsigned)p;
        if (key < best) best = key;
      }
    }
    red[tid] = best;
    __syncthreads();
    for (int offr = 128; offr > 0; offr >>= 1) {
      if (tid < offr) { if (red[tid + offr] < red[tid]) red[tid] = red[tid + offr]; }
      __syncthreads();
    }
    if (tid == 0) s_sel[k] = (int)(red[0] & 0xffffffffu);
    __syncthreads();
  }
  if (tid == 0) {
    for (int k = 0; k < SELMAX; ++k) {
      int s = (k < dyn) ? s_sel[k] : -1;
      colsel[((size_t)(b * NG + g)) * SELMAX + k] = s;
      if (s >= 0) {
        atomicAdd(&rowcnt[rowbase + s], 1);
        atomicMin(&rowassign[rowbase + s], g);
      }
    }
  }
}

// Per-row argmin over g (first occurrence) — the one-hot target for prior rows.
__global__ __launch_bounds__(256) void rowmin_kernel(const float* __restrict__ cost,
                                                     int* __restrict__ rowmin) {
  int b = blockIdx.y, p = blockIdx.x * 256 + threadIdx.x;
  if (p >= NP) return;
  float best = INFINITY;
  int bg = 0;
  for (int g = 0; g < NG; ++g) {
    float v = cost[((size_t)(b * NG + g)) * NP + p];
    if (v < best) { best = v; bg = g; }
  }
  rowmin[(size_t)b * NP + p] = bg;
}

// Column counts after prior-row one-hot replacement:
// (a) selected rows that stayed (rowcnt==1), (b) prior rows scatter to rowmin.
__global__ void colcnt_a_kernel(const int* __restrict__ colsel,
                                const int* __restrict__ rowcnt,
                                int* __restrict__ colcnt) {
  int i = blockIdx.x * 256 + threadIdx.x;
  if (i >= NB * NG) return;
  int b = i / NG;
  int cnt = 0;
  for (int k = 0; k < SELMAX; ++k) {
    int s = colsel[(size_t)i * SELMAX + k];
    if (s >= 0 && rowcnt[(size_t)b * NP + s] == 1) cnt++;
  }
  colcnt[i] = cnt;
}

__global__ void colcnt_b_kernel(const int* __restrict__ rowcnt,
                                const int* __restrict__ rowmin,
                                int* __restrict__ colcnt) {
  int b = blockIdx.y, p = blockIdx.x * 256 + threadIdx.x;
  if (p >= NP) return;
  size_t idx = (size_t)b * NP + p;
  if (rowcnt[idx] > 1) atomicAdd(&colcnt[b * NG + rowmin[idx]], 1);
}

// Single while-loop body: each still-empty column takes argmin over
// never-matched rows (the +INF2 exclusion is exact: matched rows can't win).
__global__ __launch_bounds__(256) void fixup_kernel(const float* __restrict__ cost,
                                                    const int* __restrict__ colcnt,
                                                    const int* __restrict__ rowcnt,
                                                    int* __restrict__ rowassign) {
  const int g = blockIdx.x, b = blockIdx.y, tid = threadIdx.x;
  if (colcnt[b * NG + g] != 0) return;  // uniform across block
  const size_t cbase = ((size_t)(b * NG + g)) * NP;
  const size_t rowbase = (size_t)b * NP;
  u64 best = ~0ull;
  for (int p = tid; p < NP; p += 256) {
    if (rowcnt[rowbase + p] == 0) {
      u64 key = ((u64)fkey(cost[cbase + p]) << 32) | (unsigned)p;
      if (key < best) best = key;
    }
  }
  __shared__ u64 red[256];
  red[tid] = best;
  __syncthreads();
  for (int offr = 128; offr > 0; offr >>= 1) {
    if (tid < offr) { if (red[tid + offr] < red[tid]) red[tid] = red[tid + offr]; }
    __syncthreads();
  }
  if (tid == 0) {
    int pos = (int)(red[0] & 0xffffffffu);
    atomicMin(&rowassign[rowbase + pos], g);  // min g == argmax first-1
  }
}

__global__ void output_kernel(const int* __restrict__ rowcnt,
                              const int* __restrict__ rowassign,
                              const int* __restrict__ rowmin,
                              int* __restrict__ out) {
  int b = blockIdx.y, p = blockIdx.x * 256 + threadIdx.x;
  if (p >= NP) return;
  size_t idx = (size_t)b * NP + p;
  int rc = rowcnt[idx];
  int fg, m;
  if (rc == 0) {
    int ra = rowassign[idx];
    if (ra == 0x7fffffff) { fg = 0; m = -1; }
    else { fg = 1; m = ra; }          // fixup-assigned (min g)
  } else if (rc == 1) {
    fg = 1; m = rowassign[idx];       // single selecting column
  } else {
    fg = 1; m = rowmin[idx];          // prior row -> one-hot at row argmin
  }
  out[idx] = fg;
  out[(size_t)NB * NP + idx] = m;
}

// ---------------------------------------------------------------------------
extern "C" void kernel_launch(void* const* d_in, const int* in_sizes, int n_in,
                              void* d_out, int out_size, void* d_ws, size_t ws_size,
                              hipStream_t stream) {
  const float* pred_logits = (const float*)d_in[0];
  const float* pred_boxes = (const float*)d_in[1];
  const float* gt_boxes = (const float*)d_in[2];
  const int* gt_labels = (const int*)d_in[3];
  const int* head = (const int*)d_in[4];
  (void)in_sizes; (void)n_in; (void)out_size; (void)ws_size;

  char* w = (char*)d_ws;
  size_t off = 0;
  auto alloc = [&](size_t bytes) -> void* {
    void* p = w + off;
    off += (bytes + 255) & ~(size_t)255;
    return p;
  };
  float* cost = (float*)alloc((size_t)NB * NG * NP * 4);       // 49.2 MB
  float* paux = (float*)alloc((size_t)15 * NB * NP * 4);       // 5.8 MB
  float* clst = (float*)alloc((size_t)NC * NB * NP * 4);       // 3.8 MB
  int* validArr = (int*)alloc((size_t)NB * NP * 4);
  float* gtaux = (float*)alloc((size_t)NB * NG * 22 * 4);
  int* colsel = (int*)alloc((size_t)NB * NG * SELMAX * 4);
  int* rowcnt = (int*)alloc((size_t)NB * NP * 4);
  int* rowassign = (int*)alloc((size_t)NB * NP * 4);
  int* rowmin = (int*)alloc((size_t)NB * NP * 4);
  int* colcnt = (int*)alloc((size_t)NB * NG * 4);

  int* out = (int*)d_out;
  dim3 blk(256);
  init_kernel<<<dim3((NB * NP + 255) / 256), blk, 0, stream>>>(rowcnt, rowassign);
  prep_gt_kernel<<<dim3(NB), dim3(128), 0, stream>>>(gt_boxes, gt_labels, gtaux);
  prep_pred_kernel<<<dim3((NP + 255) / 256, NB), blk, 0, stream>>>(
      pred_logits, pred_boxes, gtaux, paux, clst, validArr);
  column_kernel<<<dim3(NG, NB), blk, 0, stream>>>(
      paux, clst, validArr, gtaux, head, cost, colsel, rowcnt, rowassign);
  rowmin_kernel<<<dim3((NP + 255) / 256, NB), blk, 0, stream>>>(cost, rowmin);
  colcnt_a_kernel<<<dim3((NB * NG + 255) / 256), blk, 0, stream>>>(colsel, rowcnt, colcnt);
  colcnt_b_kernel<<<dim3((NP + 255) / 256, NB), blk, 0, stream>>>(rowcnt, rowmin, colcnt);
  fixup_kernel<<<dim3(NG, NB), blk, 0, stream>>>(cost, colcnt, rowcnt, rowassign);
  output_kernel<<<dim3((NP + 255) / 256, NB), blk, 0, stream>>>(rowcnt, rowassign, rowmin, out);
}

// Round 3
// 122.429 us; speedup vs baseline: 2.1445x; 2.1445x over previous
//
#include <hip/hip_runtime.h>
#include <stdint.h>
#include <math.h>

#define NB 16
#define NP 6000
#define NG 128
#define NC 10
#define CHUNK 24     // ceil(NP/256)
#define SELMAX 8     // dyn <= 4 for head_idx=5; slack for safety
#define GSTR 24      // padded per-GT stride (16B aligned for float4 LDS reads)

static_assert(CHUNK * 256 >= NP, "chunk covers P");

typedef unsigned long long u64;

__device__ __forceinline__ uint32_t fkey(float f) {
  // monotone float->uint mapping for (cost, idx) lexicographic ordering
  uint32_t u = __float_as_uint(f);
  return (u & 0x80000000u) ? ~u : (u | 0x80000000u);
}
__device__ __forceinline__ float fkey_inv(uint32_t k) {
  uint32_t u = (k & 0x80000000u) ? (k & 0x7fffffffu) : ~k;
  return __uint_as_float(u);
}
__device__ __forceinline__ u64 shfl_xor_u64(u64 v, int m) {
  uint32_t lo = (uint32_t)v, hi = (uint32_t)(v >> 32);
  lo = (uint32_t)__shfl_xor((int)lo, m, 64);
  hi = (uint32_t)__shfl_xor((int)hi, m, 64);
  return ((u64)hi << 32) | lo;
}

// ---------------------------------------------------------------------------
// Per-GT derived quantities, padded to GSTR floats per (b,g):
// [0:3) gmin, [3:6) gmax, [6:9) ctr lo, [9:12) ctr hi, [12:20) gt_norm,
// [20] vg, [21] label bits.
__global__ void prep_gt_kernel(const float* __restrict__ gt_boxes,
                               const int* __restrict__ gt_labels,
                               float* __restrict__ gtaux) {
#pragma clang fp contract(off)
  int b = blockIdx.x, g = threadIdx.x;
  if (g >= NG) return;
  const float* gb = gt_boxes + ((size_t)b * NG + g) * 7;
  float cx = gb[0], cy = gb[1], cz = gb[2];
  float dx = gb[3], dy = gb[4], dz = gb[5];
  float yaw = gb[6];
  float cyw = cosf(yaw), syw = sinf(yaw);
  float ca = fabsf(cyw), sa = fabsf(syw);
  float hx = 0.5f * (dx * ca + dy * sa);
  float hy = 0.5f * (dx * sa + dy * ca);
  float hz = 0.5f * dz;
  float gmin0 = cx - hx, gmin1 = cy - hy, gmin2 = cz - hz;
  float gmax0 = cx + hx, gmax1 = cy + hy, gmax2 = cz + hz;
  float vg = ((gmax0 - gmin0) * (gmax1 - gmin1)) * (gmax2 - gmin2);
  float* o = gtaux + ((size_t)b * NG + g) * GSTR;
  o[0] = gmin0; o[1] = gmin1; o[2] = gmin2;
  o[3] = gmax0; o[4] = gmax1; o[5] = gmax2;
  o[6] = cx - 1.5f * dx; o[7] = cy - 1.5f * dy; o[8] = cz - 1.5f * dz;
  o[9] = cx + 1.5f * dx; o[10] = cy + 1.5f * dy; o[11] = cz + 1.5f * dz;
  o[12] = cx; o[13] = cy; o[14] = cz;
  o[15] = logf(dx); o[16] = logf(dy); o[17] = logf(dz);
  o[18] = syw; o[19] = cyw;
  o[20] = vg;
  o[21] = __int_as_float(gt_labels[(size_t)b * NG + g]);
  o[22] = 0.0f; o[23] = 0.0f;
}

// ---------------------------------------------------------------------------
// Fused: per-pred focal table + box decode + full cost/iou matrix row +
// valid flag + row argmin + rowcnt/rowassign init.  Pred-per-thread, GT data
// LDS-resident -> each pred read exactly once from global.
// cost is stored WITHOUT the row-uniform (~valid)*INF1 term; consumers add it
// (bit-identical: reference also adds it last).
__global__ __launch_bounds__(256) void costmat_kernel(
    const float* __restrict__ pred_logits,
    const float* __restrict__ pred_boxes,
    const float* __restrict__ gtaux,
    float* __restrict__ cost,
    float* __restrict__ iouM,
    int* __restrict__ validArr,
    int* __restrict__ rowminArr,
    int* __restrict__ rowcnt,
    int* __restrict__ rowassign) {
#pragma clang fp contract(off)
  __shared__ __align__(16) float shg[NG * GSTR];     // 12 KiB
  __shared__ float shcls[256 * 11];                  // 11 KiB, stride 11 = 2-way free
  const int b = blockIdx.y, tid = threadIdx.x;
  for (int j = tid; j < NG * GSTR; j += 256)
    shg[j] = gtaux[(size_t)b * NG * GSTR + j];
  const int p = blockIdx.x * 256 + tid;
  const size_t idx = (size_t)b * NP + p;
  if (p < NP) {
    const float* lg = pred_logits + idx * NC;
    for (int c = 0; c < NC; ++c) {
      float x = lg[c];
      float pr = 1.0f / (1.0f + expf(-x));
      float neg = (-logf(1.0f - pr + 1e-12f) * 0.75f) * (pr * pr);
      float pos = (-logf(pr + 1e-12f) * 0.25f) * ((1.0f - pr) * (1.0f - pr));
      shcls[tid * 11 + c] = (pos - neg) * 2.0f;
    }
  }
  __syncthreads();
  if (p >= NP) return;

  const float* bx = pred_boxes + idx * 10;
  float b0 = bx[0], b1 = bx[1], b2 = bx[2], b3 = bx[3], b4 = bx[4];
  float b5 = bx[5], b6 = bx[6], b7 = bx[7];
  float yaw = atan2f(b6, b7);
  float d0 = expf(b3), d1 = expf(b4), d2 = expf(b5);
  float ca = fabsf(cosf(yaw)), sa = fabsf(sinf(yaw));
  float hx = 0.5f * (d0 * ca + d1 * sa);
  float hy = 0.5f * (d0 * sa + d1 * ca);
  float hz = 0.5f * d2;
  float pmin0 = b0 - hx, pmin1 = b1 - hy, pmin2 = b2 - hz;
  float pmax0 = b0 + hx, pmax1 = b1 + hy, pmax2 = b2 + hz;
  float vp = ((pmax0 - pmin0) * (pmax1 - pmin1)) * (pmax2 - pmin2);

  int valid = 0;
  float best = INFINITY;
  int bg = 0;
  size_t cidx = (size_t)b * NG * NP + p;   // advances by NP per g
  for (int g = 0; g < NG; ++g) {
    const float* s = &shg[g * GSTR];
    float4 q0 = *(const float4*)(s + 0);    // gmin0..2, gmax0
    float4 q1 = *(const float4*)(s + 4);    // gmax1..2, lo0..1
    float4 q2 = *(const float4*)(s + 8);    // lo2, hi0..2
    float4 q3 = *(const float4*)(s + 12);   // gtn0..3
    float4 q4 = *(const float4*)(s + 16);   // gtn4..7
    float2 q5 = *(const float2*)(s + 20);   // vg, label
    float gmin0 = q0.x, gmin1 = q0.y, gmin2 = q0.z;
    float gmax0 = q0.w, gmax1 = q1.x, gmax2 = q1.y;
    float lo0 = q1.z, lo1 = q1.w, lo2 = q2.x;
    float hi0 = q2.y, hi1 = q2.z, hi2 = q2.w;
    int label = __float_as_int(q5.y);
    float cls = shcls[tid * 11 + label];
    // sequential 8-term L1, mirrors jnp sum order
    float r = fabsf(b0 - q3.x);
    r = r + fabsf(b1 - q3.y);
    r = r + fabsf(b2 - q3.z);
    r = r + fabsf(b3 - q3.w);
    r = r + fabsf(b4 - q4.x);
    r = r + fabsf(b5 - q4.y);
    r = r + fabsf(b6 - q4.z);
    r = r + fabsf(b7 - q4.w);
    float reg = r * 0.25f;
    float li0 = fmaxf(pmin0, gmin0), li1 = fmaxf(pmin1, gmin1), li2 = fmaxf(pmin2, gmin2);
    float hj0 = fminf(pmax0, gmax0), hj1 = fminf(pmax1, gmax1), hj2 = fminf(pmax2, gmax2);
    float e0 = fmaxf(hj0 - li0, 0.0f), e1 = fmaxf(hj1 - li1, 0.0f), e2 = fmaxf(hj2 - li2, 0.0f);
    float inter = (e0 * e1) * e2;
    float iou = inter / (((vp + q5.x) - inter) + 1e-7f);
    bool inb = (b0 > gmin0) && (b0 < gmax0) && (b1 > gmin1) &&
               (b1 < gmax1) && (b2 > gmin2) && (b2 < gmax2);
    bool inc = (b0 > lo0) && (b0 < hi0) && (b1 > lo1) && (b1 < hi1) &&
               (b2 > lo2) && (b2 < hi2);
    float cc = ((cls + reg) + (-(iou * 0.25f))) + ((inb && inc) ? 0.0f : 100.0f);
    cost[cidx] = cc;
    iouM[cidx] = iou;
    cidx += NP;
    valid |= (int)(inb || inc);
    if (cc < best) { best = cc; bg = g; }   // first-g tiebreak, valid rows exact
  }
  validArr[idx] = valid;
  rowminArr[idx] = bg;
  rowcnt[idx] = 0;
  rowassign[idx] = 0x7fffffff;
}

// ---------------------------------------------------------------------------
// Per-column selection: top-5 iou (5 parallel argmax rounds) -> dyn, then dyn
// argmin rounds over cost (+valid penalty) = stable rank<dyn selection.
__global__ __launch_bounds__(256) void select_kernel(
    const float* __restrict__ cost,
    const float* __restrict__ iouM,
    const int* __restrict__ validArr,
    const int* __restrict__ head_ptr,
    int* __restrict__ colsel,
    int* __restrict__ rowcnt,
    int* __restrict__ rowassign) {
#pragma clang fp contract(off)
  const int g = blockIdx.x, b = blockIdx.y, tid = threadIdx.x;
  const int lane = tid & 63, wid = tid >> 6;
  const size_t cbase = ((size_t)(b * NG + g)) * NP;
  const size_t rowbase = (size_t)b * NP;
  float lc[CHUNK], li[CHUNK];
#pragma unroll
  for (int i = 0; i < CHUNK; ++i) {
    int p = i * 256 + tid;
    if (p < NP) {
      lc[i] = cost[cbase + p] + (validArr[rowbase + p] ? 0.0f : 10000.0f);
      li[i] = iouM[cbase + p];
    } else {
      lc[i] = INFINITY;
      li[i] = -INFINITY;
    }
  }
  __shared__ u64 sred[4];
  __shared__ float s_t5[5];
  __shared__ int s_dyn;
  __shared__ int s_sel[SELMAX];

  // 5 rounds of block-argmax on iou (values only matter; ties give equal vals)
  for (int k = 0; k < 5; ++k) {
    u64 best = 0;
#pragma unroll
    for (int i = 0; i < CHUNK; ++i) {
      u64 key = ((u64)fkey(li[i]) << 32) | (unsigned)(i * 256 + tid);
      if (key > best) best = key;
    }
#pragma unroll
    for (int o = 1; o < 64; o <<= 1) {
      u64 t = shfl_xor_u64(best, o);
      if (t > best) best = t;
    }
    __syncthreads();                 // protect sred from previous round
    if (lane == 0) sred[wid] = best;
    __syncthreads();
    u64 r = sred[0];
    if (sred[1] > r) r = sred[1];
    if (sred[2] > r) r = sred[2];
    if (sred[3] > r) r = sred[3];
    if (tid == 0) s_t5[k] = fkey_inv((uint32_t)(r >> 32));
    int d = (int)(r & 0xffffffffu) - tid;    // knock winner out locally
    if (d >= 0 && (d & 255) == 0) { int ii = d >> 8; if (ii < CHUNK) li[ii] = -INFINITY; }
  }
  __syncthreads();
  if (tid == 0) {
    float s = (((s_t5[0] + s_t5[1]) + s_t5[2]) + s_t5[3]) + s_t5[4];  // desc order
    float adj = s - 0.5f * (float)(6 - head_ptr[0]);
    int dyn = (int)adj;              // trunc toward zero == astype(int32)
    if (dyn < 1) dyn = 1;
    if (dyn > SELMAX) dyn = SELMAX;
    s_dyn = dyn;
  }
  __syncthreads();
  const int dyn = s_dyn;

  for (int k = 0; k < dyn; ++k) {
    u64 best = ~0ull;
#pragma unroll
    for (int i = 0; i < CHUNK; ++i) {
      u64 key = ((u64)fkey(lc[i]) << 32) | (unsigned)(i * 256 + tid);
      if (key < best) best = key;
    }
#pragma unroll
    for (int o = 1; o < 64; o <<= 1) {
      u64 t = shfl_xor_u64(best, o);
      if (t < best) best = t;
    }
    __syncthreads();
    if (lane == 0) sred[wid] = best;
    __syncthreads();
    u64 r = sred[0];
    if (sred[1] < r) r = sred[1];
    if (sred[2] < r) r = sred[2];
    if (sred[3] < r) r = sred[3];
    int pw = (int)(r & 0xffffffffu);
    if (tid == 0) s_sel[k] = pw;
    int d = pw - tid;
    if (d >= 0 && (d & 255) == 0) { int ii = d >> 8; if (ii < CHUNK) lc[ii] = INFINITY; }
  }
  __syncthreads();
  if (tid == 0) {
    for (int k = 0; k < SELMAX; ++k) {
      int s = (k < dyn) ? s_sel[k] : -1;
      colsel[((size_t)(b * NG + g)) * SELMAX + k] = s;
      if (s >= 0) {
        atomicAdd(&rowcnt[rowbase + s], 1);
        atomicMin(&rowassign[rowbase + s], g);
      }
    }
  }
}

// Column counts after prior-row one-hot replacement:
// (a) selected rows that stayed (rowcnt==1), (b) prior rows scatter to rowmin.
__global__ void colcnt_a_kernel(const int* __restrict__ colsel,
                                const int* __restrict__ rowcnt,
                                int* __restrict__ colcnt) {
  int i = blockIdx.x * 256 + threadIdx.x;
  if (i >= NB * NG) return;
  int b = i / NG;
  int cnt = 0;
  for (int k = 0; k < SELMAX; ++k) {
    int s = colsel[(size_t)i * SELMAX + k];
    if (s >= 0 && rowcnt[(size_t)b * NP + s] == 1) cnt++;
  }
  colcnt[i] = cnt;
}

__global__ void colcnt_b_kernel(const int* __restrict__ rowcnt,
                                const int* __restrict__ rowmin,
                                int* __restrict__ colcnt) {
  int b = blockIdx.y, p = blockIdx.x * 256 + threadIdx.x;
  if (p >= NP) return;
  size_t idx = (size_t)b * NP + p;
  if (rowcnt[idx] > 1) atomicAdd(&colcnt[b * NG + rowmin[idx]], 1);
}

// Single while-loop body: each still-empty column takes argmin over
// never-matched rows (the +INF2 exclusion is exact: matched rows can't win).
__global__ __launch_bounds__(256) void fixup_kernel(const float* __restrict__ cost,
                                                    const int* __restrict__ colcnt,
                                                    const int* __restrict__ rowcnt,
                                                    const int* __restrict__ validArr,
                                                    int* __restrict__ rowassign) {
#pragma clang fp contract(off)
  const int g = blockIdx.x, b = blockIdx.y, tid = threadIdx.x;
  if (colcnt[b * NG + g] != 0) return;  // uniform across block
  const size_t cbase = ((size_t)(b * NG + g)) * NP;
  const size_t rowbase = (size_t)b * NP;
  u64 best = ~0ull;
  for (int p = tid; p < NP; p += 256) {
    if (rowcnt[rowbase + p] == 0) {
      float c = cost[cbase + p] + (validArr[rowbase + p] ? 0.0f : 10000.0f);
      u64 key = ((u64)fkey(c) << 32) | (unsigned)p;
      if (key < best) best = key;
    }
  }
  __shared__ u64 red[256];
  red[tid] = best;
  __syncthreads();
  for (int offr = 128; offr > 0; offr >>= 1) {
    if (tid < offr) { if (red[tid + offr] < red[tid]) red[tid] = red[tid + offr]; }
    __syncthreads();
  }
  if (tid == 0) {
    int pos = (int)(red[0] & 0xffffffffu);
    atomicMin(&rowassign[rowbase + pos], g);  // min g == argmax first-1
  }
}

__global__ void output_kernel(const int* __restrict__ rowcnt,
                              const int* __restrict__ rowassign,
                              const int* __restrict__ rowmin,
                              int* __restrict__ out) {
  int b = blockIdx.y, p = blockIdx.x * 256 + threadIdx.x;
  if (p >= NP) return;
  size_t idx = (size_t)b * NP + p;
  int rc = rowcnt[idx];
  int fg, m;
  if (rc == 0) {
    int ra = rowassign[idx];
    if (ra == 0x7fffffff) { fg = 0; m = -1; }
    else { fg = 1; m = ra; }          // fixup-assigned (min g)
  } else if (rc == 1) {
    fg = 1; m = rowassign[idx];       // single selecting column
  } else {
    fg = 1; m = rowmin[idx];          // prior row -> one-hot at row argmin
  }
  out[idx] = fg;
  out[(size_t)NB * NP + idx] = m;
}

// ---------------------------------------------------------------------------
extern "C" void kernel_launch(void* const* d_in, const int* in_sizes, int n_in,
                              void* d_out, int out_size, void* d_ws, size_t ws_size,
                              hipStream_t stream) {
  const float* pred_logits = (const float*)d_in[0];
  const float* pred_boxes = (const float*)d_in[1];
  const float* gt_boxes = (const float*)d_in[2];
  const int* gt_labels = (const int*)d_in[3];
  const int* head = (const int*)d_in[4];
  (void)in_sizes; (void)n_in; (void)out_size; (void)ws_size;

  char* w = (char*)d_ws;
  size_t off = 0;
  auto alloc = [&](size_t bytes) -> void* {
    void* p = w + off;
    off += (bytes + 255) & ~(size_t)255;
    return p;
  };
  float* cost = (float*)alloc((size_t)NB * NG * NP * 4);       // 49.2 MB
  float* iouM = (float*)alloc((size_t)NB * NG * NP * 4);       // 49.2 MB
  float* gtaux = (float*)alloc((size_t)NB * NG * GSTR * 4);
  int* validArr = (int*)alloc((size_t)NB * NP * 4);
  int* colsel = (int*)alloc((size_t)NB * NG * SELMAX * 4);
  int* rowcnt = (int*)alloc((size_t)NB * NP * 4);
  int* rowassign = (int*)alloc((size_t)NB * NP * 4);
  int* rowmin = (int*)alloc((size_t)NB * NP * 4);
  int* colcnt = (int*)alloc((size_t)NB * NG * 4);

  int* out = (int*)d_out;
  dim3 blk(256);
  prep_gt_kernel<<<dim3(NB), dim3(128), 0, stream>>>(gt_boxes, gt_labels, gtaux);
  costmat_kernel<<<dim3((NP + 255) / 256, NB), blk, 0, stream>>>(
      pred_logits, pred_boxes, gtaux, cost, iouM, validArr, rowmin, rowcnt, rowassign);
  select_kernel<<<dim3(NG, NB), blk, 0, stream>>>(
      cost, iouM, validArr, head, colsel, rowcnt, rowassign);
  colcnt_a_kernel<<<dim3((NB * NG + 255) / 256), blk, 0, stream>>>(colsel, rowcnt, colcnt);
  colcnt_b_kernel<<<dim3((NP + 255) / 256, NB), blk, 0, stream>>>(rowcnt, rowmin, colcnt);
  fixup_kernel<<<dim3(NG, NB), blk, 0, stream>>>(cost, colcnt, rowcnt, validArr, rowassign);
  output_kernel<<<dim3((NP + 255) / 256, NB), blk, 0, stream>>>(rowcnt, rowassign, rowmin, out);
}